// Round 1
// baseline (1623.306 us; speedup 1.0000x reference)
//
#include <hip/hip_runtime.h>
#include <math.h>

#define BB 16
#define T0 400
#define HH 512
#define T1 396
#define T2 392
#define T3 384
#define KBOT 262144

typedef __attribute__((ext_vector_type(8))) short bf16x8;
typedef __attribute__((ext_vector_type(4))) float f32x4;

__device__ __forceinline__ short f2bf(float f) {
  unsigned u = __builtin_bit_cast(unsigned, f);
  u += 0x7fff + ((u >> 16) & 1);
  return (short)(u >> 16);
}

// ---------------- ws layout (float units) ----------------
#define OFF_Y1  0u          // 3,244,032
#define OFF_Y2  3244032u
#define OFF_Y3  6455296u
#define OFF_Y4  9601024u
#define OFF_Y5  12746752u
#define OFF_M   15892480u   // 4,194,304
#define OFF_P   20086784u   // 2,097,152 (also: gemm BN-stat partials, <=198*1024 floats)
#define OFF_PP  22183936u   // 65,536 (now: atomic ticket counter)
#define OFF_H   22249472u   // 8,192
#define OFF_SC  22257664u   // 5*1024 (sc_l at +l*1024, sh_l at +l*1024+512)
#define OFF_WPK 22262784u   // 2,260,992 bf16
#define OFF_XB0 23393280u   // 409,600 bf16
#define OFF_XB1 23598080u   // 3,244,032 bf16
#define OFF_XB2 25220096u
#define OFF_XB3 26825728u
#define OFF_XB4 28398592u
#define OFF_X4F 29971456u   // 3,145,728 bf16 (frag layout)
#define OFF_X5F 31544320u

// packed-weight sub-offsets (bf16 units)
#define WP1 0
#define WP2 163840
#define WP3 950272
#define WP4 1736704
#define WP5 1998848

// -------- pack weights into MFMA A-fragment layout (bf16) --------
__global__ __launch_bounds__(256) void pack_weights(
    const float* __restrict__ w1, const float* __restrict__ w2,
    const float* __restrict__ w3, const float* __restrict__ w4,
    const float* __restrict__ w5, short* __restrict__ dst) {
  const int nelem[5] = {163840, 786432, 786432, 262144, 262144};
  const int kbv[5]   = {10, 48, 48, 16, 16};
  const int offv[5]  = {WP1, WP2, WP3, WP4, WP5};
  int widx = blockIdx.y;
  int f = blockIdx.x * 256 + threadIdx.x;
  if (f >= nelem[widx]) return;
  int j = f & 7, lane = (f >> 3) & 63, rest = f >> 9;
  int KB = kbv[widx];
  int kb = rest % KB, mt = rest / KB;
  int m = mt * 16 + (lane & 15);
  int k = kb * 32 + (lane >> 4) * 8 + j;
  float v;
  if (widx == 0) {
    int kt = k >> 6, fi = k & 63;
    v = (fi < 40) ? w1[m * 200 + fi * 5 + kt] : 0.f;
  } else if (widx <= 2) {
    const float* w = (widx == 1) ? w2 : w3;
    int kt = k >> 9, c = k & 511;
    v = w[m * 1536 + c * 3 + kt];
  } else {
    const float* w = (widx == 3) ? w4 : w5;
    v = w[m * 512 + k];
  }
  dst[offv[widx] + f] = f2bf(v);
}

// -------- input fp32 [16][400][40] -> bf16 [16][400][64] zero-padded; zero ticket --------
__global__ __launch_bounds__(256) void convert_in(
    const float* __restrict__ in, short* __restrict__ xb0, unsigned* __restrict__ cnt) {
  if (blockIdx.x == 0 && threadIdx.x == 0) *cnt = 0u;
  int row = blockIdx.x * 4 + (threadIdx.x >> 6);
  int c = threadIdx.x & 63;
  float v = (c < 40) ? in[row * 40 + c] : 0.f;
  xb0[row * 64 + c] = f2bf(v);
}

// -------- MFMA GEMM with 2-phase double-buffered pipeline + fused BN-stat epilogue ----
// Y[n][m] = sum_k Wpk[m][k] * Xb_im2col[n][k]; per-block channel (sum, sumsq) partials;
// last block (atomic ticket) reduces partials and writes sc/sh for the layer.
template <int KTAPS, int DIL, int TIN, int TOUT, int CIN>
__global__ __launch_bounds__(256) void gemm_mfma(
    const short* __restrict__ Wpk, const short* __restrict__ Xb, float* __restrict__ Y,
    float* __restrict__ Ps, unsigned* __restrict__ cnt,
    const float* __restrict__ g, const float* __restrict__ beta, float nfull,
    float* __restrict__ sc, float* __restrict__ sh) {
  constexpr int KBTOT = KTAPS * CIN / 32;
  constexpr int NIT = KTAPS * CIN / 64;
  constexpr int CSEG = CIN / 64;
  __shared__ short Bfrag[2][4096];
  int tid = threadIdx.x;
  int sn = tid >> 2;
  int cb0 = (tid & 3) * 16;
  int cb1 = cb0 + 8;
  int n_glob = blockIdx.x * 64 + sn;
  int b = n_glob / TOUT, t = n_glob - b * TOUT;
  const short* xrow = Xb + (b * TIN + t) * CIN;
  int wave = tid >> 6, lane = tid & 63;
  int wm = wave >> 1, wn = wave & 1;
  int mt0 = blockIdx.y * 4 + wm * 2;
  const short* a_base0 = Wpk + mt0 * KBTOT * 512 + lane * 8;
  const short* a_base1 = a_base0 + KBTOT * 512;
  int wo0 = (((cb0 >> 5) * 4 + (sn >> 4)) * 64 + (sn & 15) + 16 * ((cb0 & 31) >> 3)) * 8;
  int wo1 = (((cb1 >> 5) * 4 + (sn >> 4)) * 64 + (sn & 15) + 16 * ((cb1 & 31) >> 3)) * 8;
  int ro = wn * 1024 + lane * 8;
  f32x4 acc00 = {0,0,0,0}, acc01 = {0,0,0,0}, acc10 = {0,0,0,0}, acc11 = {0,0,0,0};

  // prologue: stage iteration 0
  bf16x8 a00 = *(const bf16x8*)(a_base0);
  bf16x8 a01 = *(const bf16x8*)(a_base0 + 512);
  bf16x8 a10 = *(const bf16x8*)(a_base1);
  bf16x8 a11 = *(const bf16x8*)(a_base1 + 512);
  {
    bf16x8 v0 = *(const bf16x8*)(xrow + cb0);
    bf16x8 v1 = *(const bf16x8*)(xrow + cb1);
    *(bf16x8*)&Bfrag[0][wo0] = v0;
    *(bf16x8*)&Bfrag[0][wo1] = v1;
  }
  __syncthreads();
  int cur = 0;
  #pragma unroll
  for (int it = 0; it < NIT; ++it) {
    bf16x8 nv0, nv1, na00, na01, na10, na11;
    const bool more = (it + 1 < NIT);
    if (more) {
      int it1 = it + 1;
      int kt = it1 / CSEG;
      int c0 = (it1 - kt * CSEG) * 64;
      const short* p = xrow + DIL * kt * CIN + c0;
      nv0 = *(const bf16x8*)(p + cb0);
      nv1 = *(const bf16x8*)(p + cb1);
      const short* ab0 = a_base0 + it1 * 1024;
      const short* ab1 = a_base1 + it1 * 1024;
      na00 = *(const bf16x8*)(ab0);
      na01 = *(const bf16x8*)(ab0 + 512);
      na10 = *(const bf16x8*)(ab1);
      na11 = *(const bf16x8*)(ab1 + 512);
    }
    short* bf = &Bfrag[cur][0];
    bf16x8 bk0n0 = *(const bf16x8*)(bf + ro);
    bf16x8 bk0n1 = *(const bf16x8*)(bf + ro + 512);
    bf16x8 bk1n0 = *(const bf16x8*)(bf + ro + 2048);
    bf16x8 bk1n1 = *(const bf16x8*)(bf + ro + 2560);
    acc00 = __builtin_amdgcn_mfma_f32_16x16x32_bf16(a00, bk0n0, acc00, 0, 0, 0);
    acc01 = __builtin_amdgcn_mfma_f32_16x16x32_bf16(a00, bk0n1, acc01, 0, 0, 0);
    acc10 = __builtin_amdgcn_mfma_f32_16x16x32_bf16(a10, bk0n0, acc10, 0, 0, 0);
    acc11 = __builtin_amdgcn_mfma_f32_16x16x32_bf16(a10, bk0n1, acc11, 0, 0, 0);
    acc00 = __builtin_amdgcn_mfma_f32_16x16x32_bf16(a01, bk1n0, acc00, 0, 0, 0);
    acc01 = __builtin_amdgcn_mfma_f32_16x16x32_bf16(a01, bk1n1, acc01, 0, 0, 0);
    acc10 = __builtin_amdgcn_mfma_f32_16x16x32_bf16(a11, bk1n0, acc10, 0, 0, 0);
    acc11 = __builtin_amdgcn_mfma_f32_16x16x32_bf16(a11, bk1n1, acc11, 0, 0, 0);
    if (more) {
      *(bf16x8*)&Bfrag[cur ^ 1][wo0] = nv0;
      *(bf16x8*)&Bfrag[cur ^ 1][wo1] = nv1;
      a00 = na00; a01 = na01; a10 = na10; a11 = na11;
    }
    __syncthreads();
    cur ^= 1;
  }

  int quad = lane >> 4, nl = lane & 15;
  int chq = wm * 32 + quad * 4;
  int mbase = blockIdx.y * 64 + chq;
  int nb0 = blockIdx.x * 64 + wn * 32;
  *(f32x4*)(Y + (nb0 + nl) * 512 + mbase)           = acc00;
  *(f32x4*)(Y + (nb0 + 16 + nl) * 512 + mbase)      = acc01;
  *(f32x4*)(Y + (nb0 + nl) * 512 + mbase + 16)      = acc10;
  *(f32x4*)(Y + (nb0 + 16 + nl) * 512 + mbase + 16) = acc11;

  // ---- BN-stat epilogue: per-channel (sum, sumsq) over this block's 64 rows ----
  float cs0[4], cq0[4], cs1[4], cq1[4];
  #pragma unroll
  for (int r = 0; r < 4; ++r) {
    cs0[r] = acc00[r] + acc01[r];
    cq0[r] = acc00[r] * acc00[r] + acc01[r] * acc01[r];
    cs1[r] = acc10[r] + acc11[r];
    cq1[r] = acc10[r] * acc10[r] + acc11[r] * acc11[r];
  }
  #pragma unroll
  for (int off = 1; off < 16; off <<= 1) {
    #pragma unroll
    for (int r = 0; r < 4; ++r) {
      cs0[r] += __shfl_xor(cs0[r], off);
      cq0[r] += __shfl_xor(cq0[r], off);
      cs1[r] += __shfl_xor(cs1[r], off);
      cq1[r] += __shfl_xor(cq1[r], off);
    }
  }
  if (nl == 0) {
    float* prow = Ps + (blockIdx.x * 2 + wn) * 1024 + mbase;
    #pragma unroll
    for (int r = 0; r < 4; ++r) {
      prow[r] = cs0[r];
      prow[16 + r] = cs1[r];
      prow[512 + r] = cq0[r];
      prow[528 + r] = cq1[r];
    }
  }
  __threadfence();           // release: partials visible device-wide before ticket
  __syncthreads();
  __shared__ unsigned s_done;
  if (tid == 0)
    s_done = __hip_atomic_fetch_add(cnt, 1u, __ATOMIC_ACQ_REL, __HIP_MEMORY_SCOPE_AGENT);
  __syncthreads();
  unsigned nblk = gridDim.x * gridDim.y;
  if (s_done == nblk - 1) {
    __threadfence();         // acquire: invalidate stale cached partials
    if (tid == 0) *cnt = 0u; // self-reset for next layer's gemm
    int npr = gridDim.x * 2;
    int c = tid * 2;
    float Sx = 0.f, Sy = 0.f, Qx = 0.f, Qy = 0.f;
    for (int r2 = 0; r2 < npr; ++r2) {
      const float* pr = Ps + r2 * 1024;
      float2 a = *(const float2*)(pr + c);
      float2 q = *(const float2*)(pr + 512 + c);
      Sx += a.x; Sy += a.y; Qx += q.x; Qy += q.y;
    }
    float inv_n = 1.f / nfull;
    float mx = Sx * inv_n, my = Sy * inv_n;
    float vx = Qx * inv_n - mx * mx;
    float vy = Qy * inv_n - my * my;
    float scx = g[c] * rsqrtf(vx + 1e-5f);
    float scy = g[c + 1] * rsqrtf(vy + 1e-5f);
    sc[c] = scx; sc[c + 1] = scy;
    sh[c] = beta[c] - mx * scx;
    sh[c + 1] = beta[c + 1] - my * scy;
  }
}

// -------- BN affine + relu20 + fp32->bf16, [n][512] layout --------
__global__ __launch_bounds__(256) void bn_apply_bf(
    const float* __restrict__ Y, const float* __restrict__ sc,
    const float* __restrict__ sh, short* __restrict__ Xb) {
  int idx = (blockIdx.x * 256 + threadIdx.x) * 8;
  int c = idx & 511;
  float4 a = *(const float4*)(Y + idx);
  float4 d = *(const float4*)(Y + idx + 4);
  float4 s0 = *(const float4*)(sc + c);
  float4 s1 = *(const float4*)(sc + c + 4);
  float4 h0 = *(const float4*)(sh + c);
  float4 h1 = *(const float4*)(sh + c + 4);
  bf16x8 o;
  o[0] = f2bf(fminf(fmaxf(fmaf(a.x, s0.x, h0.x), 0.f), 20.f));
  o[1] = f2bf(fminf(fmaxf(fmaf(a.y, s0.y, h0.y), 0.f), 20.f));
  o[2] = f2bf(fminf(fmaxf(fmaf(a.z, s0.z, h0.z), 0.f), 20.f));
  o[3] = f2bf(fminf(fmaxf(fmaf(a.w, s0.w, h0.w), 0.f), 20.f));
  o[4] = f2bf(fminf(fmaxf(fmaf(d.x, s1.x, h1.x), 0.f), 20.f));
  o[5] = f2bf(fminf(fmaxf(fmaf(d.y, s1.y, h1.y), 0.f), 20.f));
  o[6] = f2bf(fminf(fmaxf(fmaf(d.z, s1.z, h1.z), 0.f), 20.f));
  o[7] = f2bf(fminf(fmaxf(fmaf(d.w, s1.w, h1.w), 0.f), 20.f));
  *(bf16x8*)(Xb + idx) = o;
}

// -------- BN-apply + transpose to A-frag layout, both x4 and x5 in one launch --------
// grid (tk=6, it=8, z=32): z>>4 selects y4/y5, z&15 = batch
__global__ __launch_bounds__(256) void apply_frag(
    const float* __restrict__ Y4, const float* __restrict__ Y5,
    const float* __restrict__ SCb, short* __restrict__ X4f, short* __restrict__ X5f) {
  __shared__ float ysm[64][65];
  int tk = blockIdx.x, it = blockIdx.y;
  int sel = blockIdx.z >> 4;
  int b = blockIdx.z & 15;
  const float* Y = sel ? Y5 : Y4;
  const float* scp = SCb + (sel ? 4096 : 3072);
  const float* shp = scp + 512;
  short* Xf = sel ? X5f : X4f;
  int tid = threadIdx.x;
  int ii = (tid & 15) * 4;
  #pragma unroll
  for (int p = 0; p < 4; ++p) {
    int tt = p * 16 + (tid >> 4);
    *(float4*)&ysm[tt][ii] =
        *(const float4*)(Y + ((b * 384) + tk * 64 + tt) * 512 + it * 64 + ii);
  }
  __syncthreads();
  int i_loc = tid & 63;
  int i = it * 64 + i_loc;
  float scale = scp[i], shift = shp[i];
  int mt = it * 4 + (i_loc >> 4);
  #pragma unroll
  for (int p = 0; p < 2; ++p) {
    int tq = p * 4 + (tid >> 6);
    bf16x8 pk;
    #pragma unroll
    for (int j = 0; j < 8; ++j) {
      float v = fmaf(ysm[tq * 8 + j][i_loc], scale, shift);
      pk[j] = f2bf(fminf(fmaxf(v, 0.f), 20.f));
    }
    int kb = tk * 2 + (tq >> 2);
    int lanew = (i_loc & 15) + 16 * (tq & 3);
    *(bf16x8*)(Xf + (((b * 32 + mt) * 12 + kb) * 64 + lanew) * 8) = pk;
  }
}

// -------- outer product via MFMA, LDS-free (both operands pre-packed frags) --------
__global__ __launch_bounds__(256) void outer_mfma(
    const short* __restrict__ Af, const short* __restrict__ Bf, float* __restrict__ M) {
  int b = blockIdx.z;
  int tid = threadIdx.x, wave = tid >> 6, lane = tid & 63;
  int wm = wave >> 1, wn = wave & 1;
  int mt0 = blockIdx.y * 4 + wm * 2;
  int nt0 = blockIdx.x * 4 + wn * 2;
  const short* pa0 = Af + (b * 32 + mt0) * 12 * 512 + lane * 8;
  const short* pa1 = pa0 + 12 * 512;
  const short* pb0 = Bf + (b * 32 + nt0) * 12 * 512 + lane * 8;
  const short* pb1 = pb0 + 12 * 512;
  f32x4 acc00 = {0,0,0,0}, acc01 = {0,0,0,0}, acc10 = {0,0,0,0}, acc11 = {0,0,0,0};
  #pragma unroll 4
  for (int kb = 0; kb < 12; ++kb) {
    bf16x8 a0 = *(const bf16x8*)(pa0 + kb * 512);
    bf16x8 a1 = *(const bf16x8*)(pa1 + kb * 512);
    bf16x8 b0 = *(const bf16x8*)(pb0 + kb * 512);
    bf16x8 b1 = *(const bf16x8*)(pb1 + kb * 512);
    acc00 = __builtin_amdgcn_mfma_f32_16x16x32_bf16(a0, b0, acc00, 0, 0, 0);
    acc01 = __builtin_amdgcn_mfma_f32_16x16x32_bf16(a0, b1, acc01, 0, 0, 0);
    acc10 = __builtin_amdgcn_mfma_f32_16x16x32_bf16(a1, b0, acc10, 0, 0, 0);
    acc11 = __builtin_amdgcn_mfma_f32_16x16x32_bf16(a1, b1, acc11, 0, 0, 0);
  }
  int quad = lane >> 4, nl = lane & 15;
  float* Mb = M + b * 262144;
  int i0 = blockIdx.y * 64 + wm * 32 + quad * 4;
  int j0 = blockIdx.x * 64 + wn * 32 + nl;
  #pragma unroll
  for (int r = 0; r < 4; ++r) {
    Mb[(i0 + r) * 512 + j0]           = acc00[r];
    Mb[(i0 + r) * 512 + j0 + 16]      = acc01[r];
    Mb[(i0 + 16 + r) * 512 + j0]      = acc10[r];
    Mb[(i0 + 16 + r) * 512 + j0 + 16] = acc11[r];
  }
}

// -------- bottleneck split-K with reg-staged prefetch (HBM-bound on 537MB W) --------
__global__ __launch_bounds__(256) void bot_partial_kernel(
    const float* __restrict__ m, const float* __restrict__ W, float* __restrict__ P) {
  __shared__ float Ws[32][128];
  __shared__ float Ms[32][16];
  int ic = blockIdx.x;
  int n0 = blockIdx.y * 128;
  int tid = threadIdx.x;
  int kb = ic * 1024;
  int wr = tid >> 1;
  int wc = (tid & 1) * 16;
  int nl = (tid & 63) * 2;
  int bq = (tid >> 6) * 4;
  int mrow = tid >> 3, mkg = (tid & 7) * 4;
  const float* wrow = W + (n0 + wr) * KBOT;
  const float* mrowp = m + mrow * KBOT;
  float acc[4][2] = {};
  float4 wbuf[4];
  float4 mbuf = make_float4(0.f, 0.f, 0.f, 0.f);
  #pragma unroll
  for (int q = 0; q < 4; ++q) wbuf[q] = *(const float4*)(wrow + kb + wc + q * 4);
  if (tid < 128) mbuf = *(const float4*)(mrowp + kb + mkg);
  for (int k0 = kb; k0 < kb + 1024; k0 += 32) {
    #pragma unroll
    for (int q = 0; q < 4; ++q) {
      Ws[wc + q * 4 + 0][wr] = wbuf[q].x;
      Ws[wc + q * 4 + 1][wr] = wbuf[q].y;
      Ws[wc + q * 4 + 2][wr] = wbuf[q].z;
      Ws[wc + q * 4 + 3][wr] = wbuf[q].w;
    }
    if (tid < 128) {
      Ms[mkg + 0][mrow] = mbuf.x;
      Ms[mkg + 1][mrow] = mbuf.y;
      Ms[mkg + 2][mrow] = mbuf.z;
      Ms[mkg + 3][mrow] = mbuf.w;
    }
    __syncthreads();
    if (k0 + 32 < kb + 1024) {  // prefetch next chunk while FMAs run
      #pragma unroll
      for (int q = 0; q < 4; ++q) wbuf[q] = *(const float4*)(wrow + k0 + 32 + wc + q * 4);
      if (tid < 128) mbuf = *(const float4*)(mrowp + k0 + 32 + mkg);
    }
    #pragma unroll
    for (int kk = 0; kk < 32; ++kk) {
      float2 w2 = *(const float2*)&Ws[kk][nl];
      float4 m4 = *(const float4*)&Ms[kk][bq];
      acc[0][0] = fmaf(m4.x, w2.x, acc[0][0]); acc[0][1] = fmaf(m4.x, w2.y, acc[0][1]);
      acc[1][0] = fmaf(m4.y, w2.x, acc[1][0]); acc[1][1] = fmaf(m4.y, w2.y, acc[1][1]);
      acc[2][0] = fmaf(m4.z, w2.x, acc[2][0]); acc[2][1] = fmaf(m4.z, w2.y, acc[2][1]);
      acc[3][0] = fmaf(m4.w, w2.x, acc[3][0]); acc[3][1] = fmaf(m4.w, w2.y, acc[3][1]);
    }
    __syncthreads();
  }
  #pragma unroll
  for (int i = 0; i < 4; ++i) {
    float* row = P + (ic * 16 + bq + i) * 512 + n0;
    *(float2*)&row[nl] = make_float2(acc[i][0], acc[i][1]);
  }
}

__global__ __launch_bounds__(256) void bot_reduce_kernel(
    const float* __restrict__ P, float* __restrict__ h) {
  int idx = blockIdx.x * 256 + threadIdx.x;
  float s[8] = {};
  for (int ic = 0; ic < 256; ic += 8) {
    #pragma unroll
    for (int q = 0; q < 8; ++q) s[q] += P[(ic + q) * 8192 + idx];
  }
  h[idx] = ((s[0] + s[1]) + (s[2] + s[3])) + ((s[4] + s[5]) + (s[6] + s[7]));
}

// -------- bn2d + relu20 + emb GEMV + L2-normalize*10 --------
__global__ __launch_bounds__(512) void final_kernel(
    const float* __restrict__ h, const float* __restrict__ gb, const float* __restrict__ bb,
    const float* __restrict__ embw, const float* __restrict__ embb, float* __restrict__ out) {
  __shared__ float hn[512];
  __shared__ float red[8];
  int b = blockIdx.x, e = threadIdx.x;
  float s = 0.f, s2 = 0.f;
  #pragma unroll
  for (int q = 0; q < BB; ++q) {
    float v = h[q * 512 + e];
    s += v; s2 = fmaf(v, v, s2);
  }
  float mean = s * (1.f / BB);
  float var = s2 * (1.f / BB) - mean * mean;
  float scale = gb[e] * rsqrtf(var + 1e-5f);
  float val = fmaf(h[b * 512 + e] - mean, scale, bb[e]);
  hn[e] = fminf(fmaxf(val, 0.f), 20.f);
  __syncthreads();
  float acc = 0.f;
  const float* wr = embw + e * 512;
  for (int c = 0; c < 512; c += 4) {
    float4 w4 = *(const float4*)(wr + c);
    float4 h4 = *(const float4*)&hn[c];
    acc = fmaf(w4.x, h4.x, acc); acc = fmaf(w4.y, h4.y, acc);
    acc = fmaf(w4.z, h4.z, acc); acc = fmaf(w4.w, h4.w, acc);
  }
  acc += embb[e];
  float sq = acc * acc;
  #pragma unroll
  for (int off = 32; off > 0; off >>= 1) sq += __shfl_down(sq, off);
  if ((e & 63) == 0) red[e >> 6] = sq;
  __syncthreads();
  float tot = 0.f;
  #pragma unroll
  for (int q = 0; q < 8; ++q) tot += red[q];
  float norm = sqrtf(tot + 1e-10f);
  out[b * 512 + e] = acc * (10.f / norm);
}

extern "C" void kernel_launch(void* const* d_in, const int* in_sizes, int n_in,
                              void* d_out, int out_size, void* d_ws, size_t ws_size,
                              hipStream_t stream) {
  const float* input_x = (const float*)d_in[0];
  const float* w1 = (const float*)d_in[1];
  const float* g1 = (const float*)d_in[3];  const float* b1 = (const float*)d_in[4];
  const float* w2 = (const float*)d_in[5];
  const float* g2 = (const float*)d_in[7];  const float* b2 = (const float*)d_in[8];
  const float* w3 = (const float*)d_in[9];
  const float* g3 = (const float*)d_in[11]; const float* b3 = (const float*)d_in[12];
  const float* w4 = (const float*)d_in[13];
  const float* g4 = (const float*)d_in[15]; const float* b4 = (const float*)d_in[16];
  const float* w5 = (const float*)d_in[17];
  const float* g5 = (const float*)d_in[19]; const float* b5 = (const float*)d_in[20];
  const float* botw = (const float*)d_in[21];
  const float* gb = (const float*)d_in[23]; const float* bb = (const float*)d_in[24];
  const float* embw = (const float*)d_in[25]; const float* embb = (const float*)d_in[26];

  float* ws = (float*)d_ws;
  float* y1 = ws + OFF_Y1;
  float* y2 = ws + OFF_Y2;
  float* y3 = ws + OFF_Y3;
  float* y4 = ws + OFF_Y4;
  float* y5 = ws + OFF_Y5;
  float* M  = ws + OFF_M;
  float* P  = ws + OFF_P;
  float* Ps = ws + OFF_P;       // BN-stat partials (tower phase only; reused by P later)
  unsigned* cnt = (unsigned*)(ws + OFF_PP);
  float* h  = ws + OFF_H;
  float* SC = ws + OFF_SC;
  short* WPK = (short*)(ws + OFF_WPK);
  short* xb0 = (short*)(ws + OFF_XB0);
  short* xb1 = (short*)(ws + OFF_XB1);
  short* xb2 = (short*)(ws + OFF_XB2);
  short* xb3 = (short*)(ws + OFF_XB3);
  short* xb4 = (short*)(ws + OFF_XB4);
  short* x4f = (short*)(ws + OFF_X4F);
  short* x5f = (short*)(ws + OFF_X5F);
  float* out = (float*)d_out;

  pack_weights<<<dim3(3072, 5), 256, 0, stream>>>(w1, w2, w3, w4, w5, WPK);
  convert_in<<<1600, 256, 0, stream>>>(input_x, xb0, cnt);

  gemm_mfma<5, 1, 400, 396, 64><<<dim3(99, 8), 256, 0, stream>>>(
      WPK + WP1, xb0, y1, Ps, cnt, g1, b1, 6336.f, SC + 0, SC + 512);
  bn_apply_bf<<<1584, 256, 0, stream>>>(y1, SC + 0, SC + 512, xb1);

  gemm_mfma<3, 2, 396, 392, 512><<<dim3(98, 8), 256, 0, stream>>>(
      WPK + WP2, xb1, y2, Ps, cnt, g2, b2, 6272.f, SC + 1024, SC + 1536);
  bn_apply_bf<<<1568, 256, 0, stream>>>(y2, SC + 1024, SC + 1536, xb2);

  gemm_mfma<3, 4, 392, 384, 512><<<dim3(96, 8), 256, 0, stream>>>(
      WPK + WP3, xb2, y3, Ps, cnt, g3, b3, 6144.f, SC + 2048, SC + 2560);
  bn_apply_bf<<<1536, 256, 0, stream>>>(y3, SC + 2048, SC + 2560, xb3);

  gemm_mfma<1, 0, 384, 384, 512><<<dim3(96, 8), 256, 0, stream>>>(
      WPK + WP4, xb3, y4, Ps, cnt, g4, b4, 6144.f, SC + 3072, SC + 3584);
  bn_apply_bf<<<1536, 256, 0, stream>>>(y4, SC + 3072, SC + 3584, xb4);

  gemm_mfma<1, 0, 384, 384, 512><<<dim3(96, 8), 256, 0, stream>>>(
      WPK + WP5, xb4, y5, Ps, cnt, g5, b5, 6144.f, SC + 4096, SC + 4608);

  apply_frag<<<dim3(6, 8, 32), 256, 0, stream>>>(y4, y5, SC, x4f, x5f);

  outer_mfma<<<dim3(8, 8, 16), 256, 0, stream>>>(x4f, x5f, M);
  bot_partial_kernel<<<dim3(256, 4), 256, 0, stream>>>(M, botw, P);
  bot_reduce_kernel<<<32, 256, 0, stream>>>(P, h);
  final_kernel<<<16, 512, 0, stream>>>(h, gb, bb, embw, embb, out);
}